// Round 2
// baseline (209.141 us; speedup 1.0000x reference)
//
#include <hip/hip_runtime.h>
#include <math.h>

// Problem constants (fixed by setup_inputs): B=32, C=1, H=W=512.
constexpr int HW_SIZE = 512 * 512;      // 262144 = 1 << 18
constexpr int NB      = 32;
constexpr int N       = NB * HW_SIZE;   // 8,388,608 floats per big array
constexpr int N4      = N / 4;          // 2,097,152 float4s
constexpr int GRID    = 2048;
constexpr int BLOCK   = 256;

// ws layout: acc[0]=sum(bce*m), acc[1]=sum(m), acc[2]=block-done counter
__global__ __launch_bounds__(BLOCK) void loss_reduce(
    const float4* __restrict__ x4,
    const float*  __restrict__ label,
    const float4* __restrict__ pm4,
    const float4* __restrict__ nm4,
    float* __restrict__ acc,
    float* __restrict__ out) {
  float s_bce = 0.0f;
  float s_cnt = 0.0f;

  const int stride = GRID * BLOCK;
  int i = blockIdx.x * BLOCK + threadIdx.x;

  // N4 / (GRID*BLOCK) = 4 iterations; unroll 2x -> 2 outer iterations with
  // 6 independent 16B loads in flight each.
  for (; i + stride < N4; i += 2 * stride) {
    const float4 xv0 = x4[i];
    const float4 pv0 = pm4[i];
    const float4 nv0 = nm4[i];
    const float4 xv1 = x4[i + stride];
    const float4 pv1 = pm4[i + stride];
    const float4 nv1 = nm4[i + stride];
    const float y0 = label[i >> 16];                 // (4*i)>>18
    const float y1 = label[(i + stride) >> 16];

    const float xs[8] = {xv0.x, xv0.y, xv0.z, xv0.w, xv1.x, xv1.y, xv1.z, xv1.w};
    const float ps[8] = {pv0.x, pv0.y, pv0.z, pv0.w, pv1.x, pv1.y, pv1.z, pv1.w};
    const float ns[8] = {nv0.x, nv0.y, nv0.z, nv0.w, nv1.x, nv1.y, nv1.z, nv1.w};
    const float ys[8] = {y0, y0, y0, y0, y1, y1, y1, y1};
#pragma unroll
    for (int j = 0; j < 8; ++j) {
      const float m  = (fminf(ps[j], ns[j]) > 0.5f) ? 1.0f : 0.0f;
      const float xi = xs[j];
      // softplus(-|x|) via hw exp/log: error ~1e-6 rel, threshold is 1.6e-2.
      const float sp  = __logf(1.0f + __expf(-fabsf(xi)));
      const float bce = fmaxf(xi, 0.0f) - xi * ys[j] + sp;
      s_bce = fmaf(bce, m, s_bce);
      s_cnt += m;
    }
  }
  // tail (none for these constants, kept for safety)
  for (; i < N4; i += stride) {
    const float4 xv = x4[i];
    const float4 pv = pm4[i];
    const float4 nv = nm4[i];
    const float y = label[i >> 16];
    const float xs[4] = {xv.x, xv.y, xv.z, xv.w};
    const float ps[4] = {pv.x, pv.y, pv.z, pv.w};
    const float ns[4] = {nv.x, nv.y, nv.z, nv.w};
#pragma unroll
    for (int j = 0; j < 4; ++j) {
      const float m  = (fminf(ps[j], ns[j]) > 0.5f) ? 1.0f : 0.0f;
      const float xi = xs[j];
      const float sp  = __logf(1.0f + __expf(-fabsf(xi)));
      const float bce = fmaxf(xi, 0.0f) - xi * y + sp;
      s_bce = fmaf(bce, m, s_bce);
      s_cnt += m;
    }
  }

  // Wave64 butterfly reduce.
#pragma unroll
  for (int off = 32; off > 0; off >>= 1) {
    s_bce += __shfl_down(s_bce, off);
    s_cnt += __shfl_down(s_cnt, off);
  }

  __shared__ float sb[4];
  __shared__ float sc[4];
  const int lane = threadIdx.x & 63;
  const int wave = threadIdx.x >> 6;
  if (lane == 0) {
    sb[wave] = s_bce;
    sc[wave] = s_cnt;
  }
  __syncthreads();
  if (threadIdx.x == 0) {
    atomicAdd(&acc[0], sb[0] + sb[1] + sb[2] + sb[3]);
    atomicAdd(&acc[1], sc[0] + sc[1] + sc[2] + sc[3]);
    __threadfence();  // make my adds visible before signaling done
    const unsigned done = (unsigned)atomicAdd(&acc[2], 1.0f);
    if (done == GRID - 1) {
      // Last block: fetch totals coherently (atomic RMW bypasses stale L1/L2)
      const float tb = atomicAdd(&acc[0], 0.0f);
      const float tc = atomicAdd(&acc[1], 0.0f);
      out[0] = tb / fmaxf(tc, 1.0f);
    }
  }
}

extern "C" void kernel_launch(void* const* d_in, const int* in_sizes, int n_in,
                              void* d_out, int out_size, void* d_ws, size_t ws_size,
                              hipStream_t stream) {
  const float4* x4    = (const float4*)d_in[0];  // cancer_logits
  const float*  label = (const float*)d_in[1];   // label (32,)
  const float4* pm4   = (const float4*)d_in[2];  // prostate_mask
  const float4* nm4   = (const float4*)d_in[3];  // needle_mask
  float* acc = (float*)d_ws;   // [0]=sum bce*m, [1]=sum m, [2]=done counter
  float* out = (float*)d_out;

  // d_ws is poisoned 0xAA before every launch — zero accumulators + counter.
  hipMemsetAsync(acc, 0, 3 * sizeof(float), stream);
  loss_reduce<<<GRID, BLOCK, 0, stream>>>(x4, label, pm4, nm4, acc, out);
}